// Round 10
// baseline (1640.101 us; speedup 1.0000x reference)
//
#include <hip/hip_runtime.h>
#include <hip/hip_bf16.h>

typedef __bf16 bf16_t;
typedef __bf16 bf16x8 __attribute__((ext_vector_type(8)));
typedef __bf16 bf16x4 __attribute__((ext_vector_type(4)));
typedef float  f32x4  __attribute__((ext_vector_type(4)));

#define BM 128
#define BN 128
#define BK 64

// pinned barrier: orders all memory ops in program order around the barrier
#define SBAR() asm volatile("s_barrier" ::: "memory")

// ---------------- cast + transpose H: H[b,d,l] f32 -> Hb (same layout, bf16)
// and HTb[b,l,d] bf16 ----------------
__global__ __launch_bounds__(256) void cast_transpose_H(
    const float* __restrict__ H, bf16_t* __restrict__ Hb,
    bf16_t* __restrict__ HTb, int D, int L) {
  __shared__ bf16_t tile[32][33];
  int b = blockIdx.z;
  int l0 = blockIdx.x * 32, d0 = blockIdx.y * 32;
  const float* Hp = H + (size_t)b * D * L;
  bf16_t* Hbp = Hb + (size_t)b * D * L;
  bf16_t* HTp = HTb + (size_t)b * L * D;
  int tx = threadIdx.x, ty = threadIdx.y;
#pragma unroll
  for (int r = 0; r < 4; r++) {
    int d = d0 + ty + r * 8;
    float v = Hp[(size_t)d * L + l0 + tx];
    bf16_t bv = (bf16_t)v;
    tile[ty + r * 8][tx] = bv;
    Hbp[(size_t)d * L + l0 + tx] = bv;
  }
  __syncthreads();
#pragma unroll
  for (int r = 0; r < 4; r++) {
    int l = l0 + ty + r * 8;
    HTp[(size_t)l * D + d0 + tx] = tile[tx][ty + r * 8];
  }
}

// cast with padded output row stride; pad columns are ZERO-filled (K-padding)
// NOTE: launch with gridDim.y == exact source row count (OOB-read safety).
__global__ void cast_w_pad(const float* __restrict__ in, bf16_t* __restrict__ out,
                           int cols, int ldo) {
  int c = blockIdx.x * 256 + threadIdx.x;
  int r = blockIdx.y;
  if (c < ldo) {
    float v = (c < cols) ? in[(size_t)r * cols + c] : 0.0f;
    out[(size_t)r * ldo + c] = (bf16_t)v;
  }
}

// zero rows [r0, r0+nr) of each batch stripe (stride sb rows) of a [*, L] bf16
__global__ void zero_rows(bf16_t* __restrict__ p, int r0, int nr, long sb, int L) {
  long i = (long)blockIdx.x * 256 + threadIdx.x;  // in units of 8 elems
  int b = blockIdx.y;
  long tot = (long)nr * L / 8;
  if (i < tot) {
    bf16x8 z = {};
    *(bf16x8*)(p + ((long)b * sb + r0) * L + i * 8) = z;
  }
}

// sum 4 fp32 split-partials -> bf16.  P layout [B][4][slab] f32, out [B][slab].
__global__ void reduce4_bf16(const float* __restrict__ P, bf16_t* __restrict__ out,
                             long slab) {
  long i4 = (long)blockIdx.x * 256 + threadIdx.x;  // f32x4 units
  int b = blockIdx.y;
  if (i4 * 4 < slab) {
    const float* p = P + (size_t)b * 4 * slab + i4 * 4;
    f32x4 v0 = *(const f32x4*)(p);
    f32x4 v1 = *(const f32x4*)(p + slab);
    f32x4 v2 = *(const f32x4*)(p + 2 * slab);
    f32x4 v3 = *(const f32x4*)(p + 3 * slab);
    f32x4 s = (v0 + v1) + (v2 + v3);
    bf16x4 o;
    o[0] = (bf16_t)s[0]; o[1] = (bf16_t)s[1];
    o[2] = (bf16_t)s[2]; o[3] = (bf16_t)s[3];
    *(bf16x4*)(out + (size_t)b * slab + i4 * 4) = o;
  }
}

// ---------------- helpers ----------------
__device__ inline bf16x8 cvt8(float4 a, float4 b) {
  bf16x8 o;
  o[0] = (bf16_t)a.x; o[1] = (bf16_t)a.y; o[2] = (bf16_t)a.z; o[3] = (bf16_t)a.w;
  o[4] = (bf16_t)b.x; o[5] = (bf16_t)b.y; o[6] = (bf16_t)b.z; o[7] = (bf16_t)b.w;
  return o;
}

__device__ inline void gload_lds16(const bf16_t* g, bf16_t* l) {
  __builtin_amdgcn_global_load_lds(
      (const __attribute__((address_space(1))) void*)g,
      (__attribute__((address_space(3))) void*)l, 16, 0, 0);
}

// stage one half-tile (128 rows x 64 bf16) into LDS (linear rows of 128B,
// 16B chunk slot s holds global chunk s ^ (row&7)). 512 threads, 2 loads each.
__device__ inline void stage_half(const bf16_t* __restrict__ src, int ld,
                                  bf16_t* lds_half, int t, int wid) {
  int r = t >> 3;                  // 0..63
  int gsl = (t & 7) ^ (r & 7);     // pre-swizzled source k-chunk
  const bf16_t* g = src + (size_t)r * ld + gsl * 8;
  gload_lds16(g, lds_half + wid * 512);
  gload_lds16(g + (size_t)64 * ld, lds_half + 4096 + wid * 512);
}

// ---------------- 256x256 8-phase GEMM: C[m][n] = sum_k A[m][k]*BT[n][k] ----
// 512 threads = 8 waves (2M x 4N), per-wave 128x64 output, BK=64,
// 128 KiB double-buffered LDS, counted vmcnt(4), pinned s_barrier, setprio.
// Only used where grid >= ~2000 blocks (rounds 4/5/8 A/B).
// EPI 0: C fp32 [m][n] — LDS-staged coalesced dwordx4 stores (nt iff NTS);
//        ldc % 4 == 0.  NTS=false keeps C L3-resident for the next consumer.
template <int EPI, bool NTS>
__global__ __launch_bounds__(512) void gemm256_bt(
    const bf16_t* __restrict__ A, long sAb, const bf16_t* __restrict__ BT, long sBb,
    void* __restrict__ Cv, long sCb, const float* __restrict__ W,
    int M, int N, int K, int lda, int ldb, int ldc) {
  __shared__ __align__(16) bf16_t As[2][256][64];  // 64 KB
  __shared__ __align__(16) bf16_t Bs[2][256][64];  // 64 KB
  int b = blockIdx.z;
  A += (size_t)b * sAb;
  BT += (size_t)b * sBb;

  // XCD-aware bijective block swizzle (m204)
  int nx = gridDim.x, ny = gridDim.y;
  int nwg = nx * ny;
  int bid = blockIdx.x + nx * blockIdx.y;
  int qq = nwg >> 3, rr = nwg & 7;
  int xcd = bid & 7, lin = bid >> 3;
  int swz = (xcd < rr ? xcd * (qq + 1) : rr * (qq + 1) + (xcd - rr) * qq) + lin;
  int m0 = (swz / ny) * 256;
  int n0 = (swz % ny) * 256;

  int t = threadIdx.x;
  int lane = t & 63, wid = t >> 6;
  int l15 = lane & 15, q = lane >> 4;
  int wm = (wid >> 2) * 128;   // wave M offset: 0 or 128
  int wn = (wid & 3) * 64;     // wave N offset: 0,64,128,192
  int NT = K >> 6;

  f32x4 acc[8][4];
#pragma unroll
  for (int i = 0; i < 8; i++)
#pragma unroll
    for (int j = 0; j < 4; j++)
#pragma unroll
      for (int e = 0; e < 4; e++) acc[i][j][e] = 0.0f;

  // prologue: B(t0) h0,h1 ; A(t0) h0,h1 ; B(t1) h0,h1  -> vmcnt(4) = t0 landed
  stage_half(BT + (size_t)(n0 + 0) * ldb, ldb, &Bs[0][0][0], t, wid);
  stage_half(BT + (size_t)(n0 + 128) * ldb, ldb, &Bs[0][128][0], t, wid);
  stage_half(A + (size_t)(m0 + 0) * lda, lda, &As[0][0][0], t, wid);
  stage_half(A + (size_t)(m0 + 128) * lda, lda, &As[0][128][0], t, wid);
  stage_half(BT + (size_t)(n0 + 0) * ldb + 64, ldb, &Bs[1][0][0], t, wid);
  stage_half(BT + (size_t)(n0 + 128) * ldb + 64, ldb, &Bs[1][128][0], t, wid);
  asm volatile("s_waitcnt vmcnt(4)" ::: "memory");
  SBAR();

  bf16x8 af[4][2];       // current m-half A fragments
  bf16x8 bF[2][2][2];    // whole-tile B fragments [c-half][frag][ks]

  for (int kt = 0; kt < NT; ++kt) {
    int buf = kt & 1;
    const bf16_t* An = A + (size_t)m0 * lda + (size_t)(kt + 1) * 64;
    const bf16_t* Bn2 = BT + (size_t)n0 * ldb + (size_t)(kt + 2) * 64;

    auto readA = [&](int mh) {
#pragma unroll
      for (int i = 0; i < 4; i++) {
        const char* rowp = (const char*)&As[buf][wm + mh * 64 + i * 16 + l15][0];
#pragma unroll
        for (int ks = 0; ks < 2; ks++)
          af[i][ks] = *(const bf16x8*)(rowp + ((((ks * 4 + q) ^ (l15 & 7))) << 4));
      }
    };
    auto readB = [&](int ch) {
#pragma unroll
      for (int j = 0; j < 2; j++) {
        const char* rowp = (const char*)&Bs[buf][wn + ch * 32 + j * 16 + l15][0];
#pragma unroll
        for (int ks = 0; ks < 2; ks++)
          bF[ch][j][ks] = *(const bf16x8*)(rowp + ((((ks * 4 + q) ^ (l15 & 7))) << 4));
      }
    };
    auto mmaq = [&](int mh, int ch) {
      __builtin_amdgcn_s_setprio(1);
#pragma unroll
      for (int i = 0; i < 4; i++)
#pragma unroll
        for (int j = 0; j < 2; j++)
#pragma unroll
          for (int ks = 0; ks < 2; ks++)
            acc[mh * 4 + i][ch * 2 + j] = __builtin_amdgcn_mfma_f32_16x16x32_bf16(
                af[i][ks], bF[ch][j][ks], acc[mh * 4 + i][ch * 2 + j], 0, 0, 0);
      __builtin_amdgcn_s_setprio(0);
    };

    // P1: read A(mh0)+B(c0); stage A-h0(kt+1) into other buffer
    readA(0);
    readB(0);
    if (kt + 1 < NT) stage_half(An, lda, &As[buf ^ 1][0][0], t, wid);
    SBAR();
    mmaq(0, 0);
    SBAR();
    // P2: read B(c1); stage A-h1(kt+1)
    readB(1);
    if (kt + 1 < NT) stage_half(An + (size_t)128 * lda, lda, &As[buf ^ 1][128][0], t, wid);
    SBAR();
    mmaq(0, 1);
    SBAR();
    // P3: read A(mh1); stage B-h0(kt+2) into THIS buffer (B reads done at P2)
    readA(1);
    if (kt + 2 < NT) stage_half(Bn2, ldb, &Bs[buf][0][0], t, wid);
    SBAR();
    mmaq(1, 0);
    SBAR();
    // P4: stage B-h1(kt+2); counted vmcnt gate (tile kt+1 fully landed)
    if (kt + 2 < NT) {
      stage_half(Bn2 + (size_t)128 * ldb, ldb, &Bs[buf][128][0], t, wid);
      asm volatile("s_waitcnt vmcnt(4)" ::: "memory");
    } else if (kt + 1 < NT) {
      asm volatile("s_waitcnt vmcnt(0)" ::: "memory");
    }
    SBAR();
    mmaq(1, 1);
    SBAR();
  }

  // ---- LDS-staged coalesced epilogue (fp32) ----
  float* sc = (float*)&As[0][0][0];
  float* Cp = (float*)Cv + (size_t)b * sCb;
#pragma unroll
  for (int ck = 0; ck < 4; ck++) {
    __syncthreads();
    if ((wid >> 2) == (ck >> 1)) {  // owner waves deposit rows [ck*64, +64)
      int igb = (ck & 1) * 4;
#pragma unroll
      for (int ii = 0; ii < 4; ii++) {
        int ig = igb + ii;
        int rl = ii * 16 + q * 4;  // local row base in [0,64)
#pragma unroll
        for (int jg = 0; jg < 4; jg++) {
          int c = wn + jg * 16 + l15;
#pragma unroll
          for (int r4 = 0; r4 < 4; r4++)
            sc[(rl + r4) * 256 + c] = acc[ig][jg][r4];
        }
      }
    }
    __syncthreads();
    int rbase0 = m0 + ck * 64;
#pragma unroll
    for (int i = 0; i < 8; i++) {
      int idx = i * 512 + t;        // float4 index in [0, 4096)
      int r = idx >> 6;             // 64 float4 per 256-col row
      int c4 = idx & 63;
      int gr = rbase0 + r;
      if (gr < M) {
        f32x4 v = *(const f32x4*)(sc + idx * 4);
        f32x4* dst = (f32x4*)(Cp + (size_t)gr * ldc) + (n0 >> 2) + c4;
        if (NTS) __builtin_nontemporal_store(v, dst);
        else *dst = v;
      }
    }
  }
}

// ---------------- 128x128 GEMM (m97 structure) ------------------------------
// C[m][n] = sum_k A[m][k] * BT[n][k]   (optional K-split via SPLITS:
// blockIdx.z = b*SPLITS + s; A/BT column-offset s*K; C fp32 += s*sCs)
// EPI 0: C fp32 [m][n] (LDS-staged coalesced epilogue; nt iff NTS; ldc%4==0)
// EPI 2: C bf16 [m][n] = acc * W[m][n]  (W fp32, row stride N)
// EPI 3: C bf16 [m][n]
template <typename AT, int EPI, bool NTS, int SPLITS>
__global__ __launch_bounds__(256) void gemm_bt(
    const AT* __restrict__ A, long sAb, const bf16_t* __restrict__ BT, long sBb,
    void* __restrict__ Cv, long sCb, const float* __restrict__ W,
    int M, int N, int K, int lda, int ldb, int ldc, long sCs) {
  constexpr bool AF32 = (sizeof(AT) == 4);
  __shared__ __align__(16) bf16_t As[BM][BK];
  __shared__ __align__(16) bf16_t Bs[BN][BK];
  int zz = blockIdx.z;
  int b = (SPLITS == 1) ? zz : zz / SPLITS;
  int s = (SPLITS == 1) ? 0 : zz - b * SPLITS;
  A += (size_t)b * sAb + (size_t)s * K;
  BT += (size_t)b * sBb + (size_t)s * K;

  // XCD-aware bijective block swizzle (m204)
  int nx = gridDim.x, ny = gridDim.y;
  int nwg = nx * ny;
  int bid = blockIdx.x + nx * blockIdx.y;
  int qq = nwg >> 3, rr = nwg & 7;
  int xcd = bid & 7, lin = bid >> 3;
  int swz = (xcd < rr ? xcd * (qq + 1) : rr * (qq + 1) + (xcd - rr) * qq) + lin;
  int m0 = (swz / ny) * BM;
  int n0 = (swz % ny) * BN;

  int t = threadIdx.x;
  int lane = t & 63, wid = t >> 6;
  int l15 = lane & 15, q = lane >> 4;
  int wm = (wid >> 1) * 64, wn = (wid & 1) * 64;

  int r0 = t >> 3;
  int sl = t & 7;
  int gsl = sl ^ (r0 & 7);
  bf16_t* lA = &As[0][0] + (size_t)wid * 512;
  bf16_t* lB = &Bs[0][0] + (size_t)wid * 512;

  f32x4 acc[4][4];
#pragma unroll
  for (int i = 0; i < 4; i++)
#pragma unroll
    for (int j = 0; j < 4; j++)
#pragma unroll
      for (int e = 0; e < 4; e++) acc[i][j][e] = 0.0f;

  for (int kb = 0; kb < K; kb += BK) {
    float4 va[4][2];
    if constexpr (AF32) {
#pragma unroll
      for (int i = 0; i < 4; i++) {
        int gm = m0 + i * 32 + r0;
        if (gm < M) {
          const float4* p = (const float4*)(A + (size_t)gm * lda + kb + gsl * 8);
          va[i][0] = p[0];
          va[i][1] = p[1];
        } else {
          va[i][0] = make_float4(0.f, 0.f, 0.f, 0.f);
          va[i][1] = make_float4(0.f, 0.f, 0.f, 0.f);
        }
      }
    }
    __syncthreads();
#pragma unroll
    for (int i = 0; i < 4; i++)
      gload_lds16(BT + (size_t)(n0 + i * 32 + r0) * ldb + kb + gsl * 8,
                  lB + i * 2048);
    if constexpr (AF32) {
#pragma unroll
      for (int i = 0; i < 4; i++)
        *(bf16x8*)(&As[0][0] + (size_t)(i * 256 + t) * 8) = cvt8(va[i][0], va[i][1]);
    } else {
#pragma unroll
      for (int i = 0; i < 4; i++)
        gload_lds16(A + (size_t)(m0 + i * 32 + r0) * lda + kb + gsl * 8,
                    lA + i * 2048);
    }
    __syncthreads();

#pragma unroll
    for (int ks = 0; ks < 2; ks++) {
      bf16x8 af[4], bfr[4];
#pragma unroll
      for (int i = 0; i < 4; i++) {
        int row = wm + i * 16 + l15;
        int off = (ks * 64 + q * 16) ^ ((l15 & 7) << 4);
        af[i] = *(const bf16x8*)((const char*)&As[row][0] + off);
      }
#pragma unroll
      for (int j = 0; j < 4; j++) {
        int row = wn + j * 16 + l15;
        int off = (ks * 64 + q * 16) ^ ((l15 & 7) << 4);
        bfr[j] = *(const bf16x8*)((const char*)&Bs[row][0] + off);
      }
#pragma unroll
      for (int i = 0; i < 4; i++)
#pragma unroll
        for (int j = 0; j < 4; j++)
          acc[i][j] = __builtin_amdgcn_mfma_f32_16x16x32_bf16(af[i], bfr[j],
                                                              acc[i][j], 0, 0, 0);
    }
  }

  if constexpr (EPI == 0) {
    // ---- LDS-staged coalesced epilogue (fp32) ----
    float* sc = (float*)&As[0][0];
    float* Cp = (float*)Cv + (size_t)b * sCb + (size_t)s * sCs;
#pragma unroll
    for (int ck = 0; ck < 4; ck++) {
      __syncthreads();
      if ((wid >> 1) == (ck >> 1)) {  // owner waves: rows [ck*32, ck*32+32)
        int ib = (ck & 1) * 2;
#pragma unroll
        for (int ii = 0; ii < 2; ii++) {
          int i = ib + ii;
          int rl = ii * 16 + q * 4;
#pragma unroll
          for (int j = 0; j < 4; j++) {
            int c = wn + j * 16 + l15;
#pragma unroll
            for (int r4 = 0; r4 < 4; r4++)
              sc[(rl + r4) * 128 + c] = acc[i][j][r4];
          }
        }
      }
      __syncthreads();
      int rbase0 = m0 + ck * 32;
#pragma unroll
      for (int i = 0; i < 4; i++) {
        int idx = i * 256 + t;      // float4 index in [0, 1024)
        int r = idx >> 5;           // 32 float4 per 128-col row
        int c4 = idx & 31;
        int gr = rbase0 + r;
        if (gr < M) {
          f32x4 v = *(const f32x4*)(sc + idx * 4);
          f32x4* dst = (f32x4*)(Cp + (size_t)gr * ldc) + (n0 >> 2) + c4;
          if (NTS) __builtin_nontemporal_store(v, dst);
          else *dst = v;
        }
      }
    }
  } else {
#pragma unroll
    for (int i = 0; i < 4; i++) {
      int rbase = m0 + wm + i * 16 + q * 4;
#pragma unroll
      for (int j = 0; j < 4; j++) {
        int c = n0 + wn + j * 16 + l15;
#pragma unroll
        for (int r4 = 0; r4 < 4; r4++) {
          int r = rbase + r4;
          if (r < M) {
            float val = acc[i][j][r4];
            if (EPI == 2) {
              float w = W[(size_t)r * N + c];
              bf16_t* Cp = (bf16_t*)Cv + (size_t)b * sCb;
              Cp[(size_t)r * ldc + c] = (bf16_t)(val * w);
            } else {
              bf16_t* Cp = (bf16_t*)Cv + (size_t)b * sCb;
              Cp[(size_t)r * ldc + c] = (bf16_t)val;
            }
          }
        }
      }
    }
  }
}

// ---------------- row softmax, L = 4096 (16 elems/thread, 256 threads) -----
// MODE 0: fp32 out (may alias in)
// MODE 1: bf16 out
// MODE 2: fp32 out (may alias in; nt — output, never re-read) + bf16 copy to
//         out2 (cacheable — re-read by step 9). E2 loads normal (serve L3
//         hits from step 7's cacheable store).
// in row  = blockIdx.y * gridDim.x + blockIdx.x
// out row = blockIdx.y * ostr      + blockIdx.x   (ostr: padded batch stride)
template <int MODE>
__global__ __launch_bounds__(256) void softmax_rows(
    const float* __restrict__ in, void* __restrict__ out,
    bf16_t* __restrict__ out2, int L, int ostr) {
  long row_in = (long)blockIdx.y * gridDim.x + blockIdx.x;
  long row_out = (long)blockIdx.y * ostr + blockIdx.x;
  const float* ip = in + row_in * L;
  int t = threadIdx.x;
  int lane = t & 63, wid = t >> 6;
  f32x4 v[4];
  float m = -3.4e38f;
#pragma unroll
  for (int c = 0; c < 4; c++) {
    v[c] = ((const f32x4*)ip)[c * 256 + t];
    m = fmaxf(m, fmaxf(fmaxf(v[c][0], v[c][1]), fmaxf(v[c][2], v[c][3])));
  }
#pragma unroll
  for (int off = 1; off < 64; off <<= 1) m = fmaxf(m, __shfl_xor(m, off));
  __shared__ float redm[4];
  __shared__ float reds[4];
  if (lane == 0) redm[wid] = m;
  __syncthreads();
  m = fmaxf(fmaxf(redm[0], redm[1]), fmaxf(redm[2], redm[3]));
  float s = 0.0f;
#pragma unroll
  for (int c = 0; c < 4; c++) {
    v[c][0] = __expf(v[c][0] - m);
    v[c][1] = __expf(v[c][1] - m);
    v[c][2] = __expf(v[c][2] - m);
    v[c][3] = __expf(v[c][3] - m);
    s += (v[c][0] + v[c][1]) + (v[c][2] + v[c][3]);
  }
#pragma unroll
  for (int off = 1; off < 64; off <<= 1) s += __shfl_xor(s, off);
  if (lane == 0) reds[wid] = s;
  __syncthreads();
  s = (reds[0] + reds[1]) + (reds[2] + reds[3]);
  float inv = 1.0f / s;
  if (MODE == 1) {
    bf16_t* op = (bf16_t*)out + row_out * L;
#pragma unroll
    for (int c = 0; c < 4; c++) {
      bf16x4 o;
      o[0] = (bf16_t)(v[c][0] * inv);
      o[1] = (bf16_t)(v[c][1] * inv);
      o[2] = (bf16_t)(v[c][2] * inv);
      o[3] = (bf16_t)(v[c][3] * inv);
      *(bf16x4*)(op + ((size_t)c * 256 + t) * 4) = o;
    }
  } else {
    float* op = (float*)out + row_out * L;
#pragma unroll
    for (int c = 0; c < 4; c++) {
      f32x4 o = v[c] * inv;
      if (MODE == 2) {
        __builtin_nontemporal_store(o, (f32x4*)op + c * 256 + t);  // A2: dead
        bf16x4 ob;
        ob[0] = (bf16_t)o[0]; ob[1] = (bf16_t)o[1];
        ob[2] = (bf16_t)o[2]; ob[3] = (bf16_t)o[3];
        *((bf16x4*)(out2 + row_out * L) + c * 256 + t) = ob;       // A2b: re-read
      } else {
        ((f32x4*)op)[c * 256 + t] = o;
      }
    }
  }
}

extern "C" void kernel_launch(void* const* d_in, const int* in_sizes, int n_in,
                              void* d_out, int out_size, void* d_ws, size_t ws_size,
                              hipStream_t stream) {
  const int B = 4, D = 512, L = 4096, N1 = 1167, N2 = 8921;
  const int N1P = 1280;  // padded N1: multiple of 128, row stride
  const int N1K = 1216;  // K extent for step 6 (smallest multiple of 64 >= N1)
  const int M2P = 8960;  // M-padded N2 (multiple of 256)
  const long SLAB5 = (long)D * N1P;  // step-5' split-partial slab (f32 elems)
  const float* H = (const float*)d_in[0];
  const float* Q1w = (const float*)d_in[1];
  const float* Q2w = (const float*)d_in[2];
  const float* Q12w = (const float*)d_in[3];
  float* C2 = (float*)d_out;                  // [B, N2, D] fp32
  float* A2 = C2 + (size_t)B * N2 * D;        // [B, N2, L] fp32 (E2 in place)

  char* ws = (char*)d_ws;
  size_t off = 0;
  auto alloc = [&](size_t bytes) -> void* {
    void* p = ws + off;
    off = (off + bytes + 255) & ~(size_t)255;
    return p;
  };
  bf16_t* Hb   = (bf16_t*)alloc((size_t)B * D * L * 2);
  bf16_t* HTb  = (bf16_t*)alloc((size_t)B * L * D * 2);
  bf16_t* Q1b  = (bf16_t*)alloc((size_t)N1P * D * 2);               // M-padded
  bf16_t* Q12b = (bf16_t*)alloc((size_t)M2P * N1P * 2);             // M+K padded
  float*  E1   = (float*)alloc((size_t)B * N1 * L * 4);
  bf16_t* A1b  = (bf16_t*)alloc((size_t)B * N1P * L * 2);           // [B][1280][L]
  bf16_t* C1Tb = (bf16_t*)alloc((size_t)B * D * N1P * 2);           // [B][512][1280]
  bf16_t* Q2b  = (bf16_t*)alloc(((size_t)B * N2 + 64) * D * 2);     // tail slop
  float*  P5   = (float*)alloc((size_t)B * 4 * SLAB5 * 4);          // 5' partials
  // bf16 copy of A2 for the step-9 GEMM (tail slop covers M-pad overreads of
  // the unguarded global_load_lds in the last batch). Guarded by ws_size.
  size_t a2b_bytes = ((size_t)B * N2 + 128) * (size_t)L * 2;
  bool useA2b = (ws_size > 0) && (off + a2b_bytes <= ws_size);
  bf16_t* A2b = (bf16_t*)alloc(a2b_bytes);

  // 1. bf16 cast of H + transpose
  cast_transpose_H<<<dim3(L / 32, D / 32, B), dim3(32, 8), 0, stream>>>(H, Hb, HTb, D, L);
  // 2. weight casts (grid.y = exact source rows; pad rows zero-filled after)
  cast_w_pad<<<dim3((D + 255) / 256, N1), 256, 0, stream>>>(Q1w, Q1b, D, D);
  zero_rows<<<dim3(((N1P - N1) * D / 8 + 255) / 256, 1), 256, 0, stream>>>(
      Q1b, N1, N1P - N1, 0, D);
  cast_w_pad<<<dim3((N1P + 255) / 256, N2), 256, 0, stream>>>(Q12w, Q12b, N1, N1P);
  zero_rows<<<dim3(((N1P - N1) * L / 8 + 255) / 256, B), 256, 0, stream>>>(
      A1b, N1, N1P - N1, (long)N1P, L);
  // 3. E1[b] = Q1 @ H[b]   (M=N1, N=L, K=D; BT = HT) [128^2]
  //    E1 (76.5 MB) fits L3 entirely and softmax1 reads it next -> CACHEABLE.
  gemm_bt<bf16_t, 0, false, 1><<<dim3(N1P / BM, L / BN, B), 256, 0, stream>>>(
      Q1b, 0, HTb, (long)L * D, E1, (long)N1 * L, nullptr, N1, L, D, D, D, L, 0);
  // 4. A1 = softmax(E1) -> bf16 rows [b*N1P + r]
  softmax_rows<1><<<dim3(N1, B), 256, 0, stream>>>(E1, A1b, nullptr, L, N1P);
  // 5'. C1T[b][d][n] = sum_l H[b,d,l] * A1[b,n,l]  (M=D, N=N1P, K=L)
  //     split-K=4 over L (640 blocks); cacheable partials, reduce -> bf16.
  gemm_bt<bf16_t, 0, false, 4><<<dim3(D / BM, N1P / BN, B * 4), 256, 0, stream>>>(
      Hb, (long)D * L, A1b, (long)N1P * L, P5, 4 * SLAB5, nullptr,
      D, N1P, L / 4, L, L, N1P, SLAB5);
  reduce4_bf16<<<dim3((SLAB5 / 4 + 255) / 256, B), 256, 0, stream>>>(P5, C1Tb, SLAB5);
  // 6. Q2[b] = (Q12 @ C1) * Q2w -> bf16  (M=N2, N=D, K=N1K; strides N1P) [128^2]
  gemm_bt<bf16_t, 2, true, 1><<<dim3(M2P / BM, D / BN, B), 256, 0, stream>>>(
      Q12b, 0, C1Tb, (long)D * N1P, Q2b, (long)N2 * D, Q2w, N2, D, N1K, N1P, N1P, D, 0);
  // 7. E2[b] = Q2 @ H[b] -> fp32 into A2 region  (M=N2, N=L, K=D)
  //    [256^2 8-phase, 2240 blocks]. E2 is re-read by softmax2 -> CACHEABLE
  //    store (tail ~250 MB can serve softmax reads from L3).
  gemm256_bt<0, false><<<dim3(M2P / 256, L / 256, B), 512, 0, stream>>>(
      Q2b, (long)N2 * D, HTb, (long)L * D, A2, (long)N2 * L, nullptr, N2, L, D, D, D, L);
  if (useA2b) {
    // 8. A2 = softmax(E2) in place (fp32 nt — output, dead) + bf16 copy
    //    (cacheable — step 9 reads it)
    softmax_rows<2><<<dim3(B * N2, 1), 256, 0, stream>>>(A2, A2, A2b, L, 0);
    // 9. C2[b] = A2 @ H[b]^T  (M=N2, N=D, K=L; bf16 A) [128^2, 1120 blocks]
    gemm_bt<bf16_t, 0, true, 1><<<dim3(M2P / BM, D / BN, B), 256, 0, stream>>>(
        A2b, (long)N2 * L, Hb, (long)D * L, C2, (long)N2 * D, nullptr, N2, D, L, L, L, D, 0);
  } else {
    // fallback: workspace too small for A2b
    softmax_rows<0><<<dim3(B * N2, 1), 256, 0, stream>>>(A2, A2, nullptr, L, 0);
    gemm_bt<float, 0, true, 1><<<dim3(M2P / BM, D / BN, B), 256, 0, stream>>>(
        A2, (long)N2 * L, Hb, (long)D * L, C2, (long)N2 * D, nullptr, N2, D, L, L, L, D, 0);
  }
}

// Round 11
// 1590.624 us; speedup vs baseline: 1.0311x; 1.0311x over previous
//
#include <hip/hip_runtime.h>
#include <hip/hip_bf16.h>

typedef __bf16 bf16_t;
typedef __bf16 bf16x8 __attribute__((ext_vector_type(8)));
typedef __bf16 bf16x4 __attribute__((ext_vector_type(4)));
typedef float  f32x4  __attribute__((ext_vector_type(4)));

#define BM 128
#define BN 128
#define BK 64

// pinned barrier: orders all memory ops in program order around the barrier
#define SBAR() asm volatile("s_barrier" ::: "memory")

// ---------------- cast + transpose H: H[b,d,l] f32 -> Hb (same layout, bf16)
// and HTb[b,l,d] bf16 ----------------
__global__ __launch_bounds__(256) void cast_transpose_H(
    const float* __restrict__ H, bf16_t* __restrict__ Hb,
    bf16_t* __restrict__ HTb, int D, int L) {
  __shared__ bf16_t tile[32][33];
  int b = blockIdx.z;
  int l0 = blockIdx.x * 32, d0 = blockIdx.y * 32;
  const float* Hp = H + (size_t)b * D * L;
  bf16_t* Hbp = Hb + (size_t)b * D * L;
  bf16_t* HTp = HTb + (size_t)b * L * D;
  int tx = threadIdx.x, ty = threadIdx.y;
#pragma unroll
  for (int r = 0; r < 4; r++) {
    int d = d0 + ty + r * 8;
    float v = Hp[(size_t)d * L + l0 + tx];
    bf16_t bv = (bf16_t)v;
    tile[ty + r * 8][tx] = bv;
    Hbp[(size_t)d * L + l0 + tx] = bv;
  }
  __syncthreads();
#pragma unroll
  for (int r = 0; r < 4; r++) {
    int l = l0 + ty + r * 8;
    HTp[(size_t)l * D + d0 + tx] = tile[tx][ty + r * 8];
  }
}

// cast with padded output row stride; pad columns are ZERO-filled (K-padding)
// NOTE: launch with gridDim.y == exact source row count (OOB-read safety).
__global__ void cast_w_pad(const float* __restrict__ in, bf16_t* __restrict__ out,
                           int cols, int ldo) {
  int c = blockIdx.x * 256 + threadIdx.x;
  int r = blockIdx.y;
  if (c < ldo) {
    float v = (c < cols) ? in[(size_t)r * cols + c] : 0.0f;
    out[(size_t)r * ldo + c] = (bf16_t)v;
  }
}

// zero rows [r0, r0+nr) of each batch stripe (stride sb rows) of a [*, L] bf16
__global__ void zero_rows(bf16_t* __restrict__ p, int r0, int nr, long sb, int L) {
  long i = (long)blockIdx.x * 256 + threadIdx.x;  // in units of 8 elems
  int b = blockIdx.y;
  long tot = (long)nr * L / 8;
  if (i < tot) {
    bf16x8 z = {};
    *(bf16x8*)(p + ((long)b * sb + r0) * L + i * 8) = z;
  }
}

// sum 4 fp32 split-partials -> bf16.  P layout [B][4][slab] f32, out [B][slab].
__global__ void reduce4_bf16(const float* __restrict__ P, bf16_t* __restrict__ out,
                             long slab) {
  long i4 = (long)blockIdx.x * 256 + threadIdx.x;  // f32x4 units
  int b = blockIdx.y;
  if (i4 * 4 < slab) {
    const float* p = P + (size_t)b * 4 * slab + i4 * 4;
    f32x4 v0 = *(const f32x4*)(p);
    f32x4 v1 = *(const f32x4*)(p + slab);
    f32x4 v2 = *(const f32x4*)(p + 2 * slab);
    f32x4 v3 = *(const f32x4*)(p + 3 * slab);
    f32x4 s = (v0 + v1) + (v2 + v3);
    bf16x4 o;
    o[0] = (bf16_t)s[0]; o[1] = (bf16_t)s[1];
    o[2] = (bf16_t)s[2]; o[3] = (bf16_t)s[3];
    *(bf16x4*)(out + (size_t)b * slab + i4 * 4) = o;
  }
}

// ---------------- helpers ----------------
__device__ inline bf16x8 cvt8(float4 a, float4 b) {
  bf16x8 o;
  o[0] = (bf16_t)a.x; o[1] = (bf16_t)a.y; o[2] = (bf16_t)a.z; o[3] = (bf16_t)a.w;
  o[4] = (bf16_t)b.x; o[5] = (bf16_t)b.y; o[6] = (bf16_t)b.z; o[7] = (bf16_t)b.w;
  return o;
}

__device__ inline void gload_lds16(const bf16_t* g, bf16_t* l) {
  __builtin_amdgcn_global_load_lds(
      (const __attribute__((address_space(1))) void*)g,
      (__attribute__((address_space(3))) void*)l, 16, 0, 0);
}

// stage one half-tile (128 rows x 64 bf16) into LDS (linear rows of 128B,
// 16B chunk slot s holds global chunk s ^ (row&7)). 512 threads, 2 loads each.
__device__ inline void stage_half(const bf16_t* __restrict__ src, int ld,
                                  bf16_t* lds_half, int t, int wid) {
  int r = t >> 3;                  // 0..63
  int gsl = (t & 7) ^ (r & 7);     // pre-swizzled source k-chunk
  const bf16_t* g = src + (size_t)r * ld + gsl * 8;
  gload_lds16(g, lds_half + wid * 512);
  gload_lds16(g + (size_t)64 * ld, lds_half + 4096 + wid * 512);
}

// ---------------- 256x256 8-phase GEMM: C[m][n] = sum_k A[m][k]*BT[n][k] ----
// 512 threads = 8 waves (2M x 4N), per-wave 128x64 output, BK=64,
// 128 KiB double-buffered LDS, counted vmcnt(4), pinned s_barrier, setprio.
// Wins where the K-loop is deep (NT >= ~32) and grid fills the chip
// (step 7: 2240 blocks, r4/5 A/B). This round isolates step 9 (NT=64, 280
// blocks) — r8's bundle couldn't attribute.
// EPI 0: C fp32 [m][n] — LDS-staged coalesced dwordx4 stores (nt iff NTS);
//        ldc % 4 == 0.
template <int EPI, bool NTS>
__global__ __launch_bounds__(512) void gemm256_bt(
    const bf16_t* __restrict__ A, long sAb, const bf16_t* __restrict__ BT, long sBb,
    void* __restrict__ Cv, long sCb, const float* __restrict__ W,
    int M, int N, int K, int lda, int ldb, int ldc) {
  __shared__ __align__(16) bf16_t As[2][256][64];  // 64 KB
  __shared__ __align__(16) bf16_t Bs[2][256][64];  // 64 KB
  int b = blockIdx.z;
  A += (size_t)b * sAb;
  BT += (size_t)b * sBb;

  // XCD-aware bijective block swizzle (m204)
  int nx = gridDim.x, ny = gridDim.y;
  int nwg = nx * ny;
  int bid = blockIdx.x + nx * blockIdx.y;
  int qq = nwg >> 3, rr = nwg & 7;
  int xcd = bid & 7, lin = bid >> 3;
  int swz = (xcd < rr ? xcd * (qq + 1) : rr * (qq + 1) + (xcd - rr) * qq) + lin;
  int m0 = (swz / ny) * 256;
  int n0 = (swz % ny) * 256;

  int t = threadIdx.x;
  int lane = t & 63, wid = t >> 6;
  int l15 = lane & 15, q = lane >> 4;
  int wm = (wid >> 2) * 128;   // wave M offset: 0 or 128
  int wn = (wid & 3) * 64;     // wave N offset: 0,64,128,192
  int NT = K >> 6;

  f32x4 acc[8][4];
#pragma unroll
  for (int i = 0; i < 8; i++)
#pragma unroll
    for (int j = 0; j < 4; j++)
#pragma unroll
      for (int e = 0; e < 4; e++) acc[i][j][e] = 0.0f;

  // prologue: B(t0) h0,h1 ; A(t0) h0,h1 ; B(t1) h0,h1  -> vmcnt(4) = t0 landed
  stage_half(BT + (size_t)(n0 + 0) * ldb, ldb, &Bs[0][0][0], t, wid);
  stage_half(BT + (size_t)(n0 + 128) * ldb, ldb, &Bs[0][128][0], t, wid);
  stage_half(A + (size_t)(m0 + 0) * lda, lda, &As[0][0][0], t, wid);
  stage_half(A + (size_t)(m0 + 128) * lda, lda, &As[0][128][0], t, wid);
  stage_half(BT + (size_t)(n0 + 0) * ldb + 64, ldb, &Bs[1][0][0], t, wid);
  stage_half(BT + (size_t)(n0 + 128) * ldb + 64, ldb, &Bs[1][128][0], t, wid);
  asm volatile("s_waitcnt vmcnt(4)" ::: "memory");
  SBAR();

  bf16x8 af[4][2];       // current m-half A fragments
  bf16x8 bF[2][2][2];    // whole-tile B fragments [c-half][frag][ks]

  for (int kt = 0; kt < NT; ++kt) {
    int buf = kt & 1;
    const bf16_t* An = A + (size_t)m0 * lda + (size_t)(kt + 1) * 64;
    const bf16_t* Bn2 = BT + (size_t)n0 * ldb + (size_t)(kt + 2) * 64;

    auto readA = [&](int mh) {
#pragma unroll
      for (int i = 0; i < 4; i++) {
        const char* rowp = (const char*)&As[buf][wm + mh * 64 + i * 16 + l15][0];
#pragma unroll
        for (int ks = 0; ks < 2; ks++)
          af[i][ks] = *(const bf16x8*)(rowp + ((((ks * 4 + q) ^ (l15 & 7))) << 4));
      }
    };
    auto readB = [&](int ch) {
#pragma unroll
      for (int j = 0; j < 2; j++) {
        const char* rowp = (const char*)&Bs[buf][wn + ch * 32 + j * 16 + l15][0];
#pragma unroll
        for (int ks = 0; ks < 2; ks++)
          bF[ch][j][ks] = *(const bf16x8*)(rowp + ((((ks * 4 + q) ^ (l15 & 7))) << 4));
      }
    };
    auto mmaq = [&](int mh, int ch) {
      __builtin_amdgcn_s_setprio(1);
#pragma unroll
      for (int i = 0; i < 4; i++)
#pragma unroll
        for (int j = 0; j < 2; j++)
#pragma unroll
          for (int ks = 0; ks < 2; ks++)
            acc[mh * 4 + i][ch * 2 + j] = __builtin_amdgcn_mfma_f32_16x16x32_bf16(
                af[i][ks], bF[ch][j][ks], acc[mh * 4 + i][ch * 2 + j], 0, 0, 0);
      __builtin_amdgcn_s_setprio(0);
    };

    // P1: read A(mh0)+B(c0); stage A-h0(kt+1) into other buffer
    readA(0);
    readB(0);
    if (kt + 1 < NT) stage_half(An, lda, &As[buf ^ 1][0][0], t, wid);
    SBAR();
    mmaq(0, 0);
    SBAR();
    // P2: read B(c1); stage A-h1(kt+1)
    readB(1);
    if (kt + 1 < NT) stage_half(An + (size_t)128 * lda, lda, &As[buf ^ 1][128][0], t, wid);
    SBAR();
    mmaq(0, 1);
    SBAR();
    // P3: read A(mh1); stage B-h0(kt+2) into THIS buffer (B reads done at P2)
    readA(1);
    if (kt + 2 < NT) stage_half(Bn2, ldb, &Bs[buf][0][0], t, wid);
    SBAR();
    mmaq(1, 0);
    SBAR();
    // P4: stage B-h1(kt+2); counted vmcnt gate (tile kt+1 fully landed)
    if (kt + 2 < NT) {
      stage_half(Bn2 + (size_t)128 * ldb, ldb, &Bs[buf][128][0], t, wid);
      asm volatile("s_waitcnt vmcnt(4)" ::: "memory");
    } else if (kt + 1 < NT) {
      asm volatile("s_waitcnt vmcnt(0)" ::: "memory");
    }
    SBAR();
    mmaq(1, 1);
    SBAR();
  }

  // ---- LDS-staged coalesced epilogue (fp32) ----
  float* sc = (float*)&As[0][0][0];
  float* Cp = (float*)Cv + (size_t)b * sCb;
#pragma unroll
  for (int ck = 0; ck < 4; ck++) {
    __syncthreads();
    if ((wid >> 2) == (ck >> 1)) {  // owner waves deposit rows [ck*64, +64)
      int igb = (ck & 1) * 4;
#pragma unroll
      for (int ii = 0; ii < 4; ii++) {
        int ig = igb + ii;
        int rl = ii * 16 + q * 4;  // local row base in [0,64)
#pragma unroll
        for (int jg = 0; jg < 4; jg++) {
          int c = wn + jg * 16 + l15;
#pragma unroll
          for (int r4 = 0; r4 < 4; r4++)
            sc[(rl + r4) * 256 + c] = acc[ig][jg][r4];
        }
      }
    }
    __syncthreads();
    int rbase0 = m0 + ck * 64;
#pragma unroll
    for (int i = 0; i < 8; i++) {
      int idx = i * 512 + t;        // float4 index in [0, 4096)
      int r = idx >> 6;             // 64 float4 per 256-col row
      int c4 = idx & 63;
      int gr = rbase0 + r;
      if (gr < M) {
        f32x4 v = *(const f32x4*)(sc + idx * 4);
        f32x4* dst = (f32x4*)(Cp + (size_t)gr * ldc) + (n0 >> 2) + c4;
        if (NTS) __builtin_nontemporal_store(v, dst);
        else *dst = v;
      }
    }
  }
}

// ---------------- 128x128 GEMM (m97 structure) ------------------------------
// C[m][n] = sum_k A[m][k] * BT[n][k]   (optional K-split via SPLITS:
// blockIdx.z = b*SPLITS + s; A/BT column-offset s*K; C fp32 += s*sCs)
// EPI 0: C fp32 [m][n] (LDS-staged coalesced epilogue; nt iff NTS; ldc%4==0)
// EPI 2: C bf16 [m][n] = acc * W[m][n]  (W fp32, row stride N)
// EPI 3: C bf16 [m][n]
template <typename AT, int EPI, bool NTS, int SPLITS>
__global__ __launch_bounds__(256) void gemm_bt(
    const AT* __restrict__ A, long sAb, const bf16_t* __restrict__ BT, long sBb,
    void* __restrict__ Cv, long sCb, const float* __restrict__ W,
    int M, int N, int K, int lda, int ldb, int ldc, long sCs) {
  constexpr bool AF32 = (sizeof(AT) == 4);
  __shared__ __align__(16) bf16_t As[BM][BK];
  __shared__ __align__(16) bf16_t Bs[BN][BK];
  int zz = blockIdx.z;
  int b = (SPLITS == 1) ? zz : zz / SPLITS;
  int s = (SPLITS == 1) ? 0 : zz - b * SPLITS;
  A += (size_t)b * sAb + (size_t)s * K;
  BT += (size_t)b * sBb + (size_t)s * K;

  // XCD-aware bijective block swizzle (m204)
  int nx = gridDim.x, ny = gridDim.y;
  int nwg = nx * ny;
  int bid = blockIdx.x + nx * blockIdx.y;
  int qq = nwg >> 3, rr = nwg & 7;
  int xcd = bid & 7, lin = bid >> 3;
  int swz = (xcd < rr ? xcd * (qq + 1) : rr * (qq + 1) + (xcd - rr) * qq) + lin;
  int m0 = (swz / ny) * BM;
  int n0 = (swz % ny) * BN;

  int t = threadIdx.x;
  int lane = t & 63, wid = t >> 6;
  int l15 = lane & 15, q = lane >> 4;
  int wm = (wid >> 1) * 64, wn = (wid & 1) * 64;

  int r0 = t >> 3;
  int sl = t & 7;
  int gsl = sl ^ (r0 & 7);
  bf16_t* lA = &As[0][0] + (size_t)wid * 512;
  bf16_t* lB = &Bs[0][0] + (size_t)wid * 512;

  f32x4 acc[4][4];
#pragma unroll
  for (int i = 0; i < 4; i++)
#pragma unroll
    for (int j = 0; j < 4; j++)
#pragma unroll
      for (int e = 0; e < 4; e++) acc[i][j][e] = 0.0f;

  for (int kb = 0; kb < K; kb += BK) {
    float4 va[4][2];
    if constexpr (AF32) {
#pragma unroll
      for (int i = 0; i < 4; i++) {
        int gm = m0 + i * 32 + r0;
        if (gm < M) {
          const float4* p = (const float4*)(A + (size_t)gm * lda + kb + gsl * 8);
          va[i][0] = p[0];
          va[i][1] = p[1];
        } else {
          va[i][0] = make_float4(0.f, 0.f, 0.f, 0.f);
          va[i][1] = make_float4(0.f, 0.f, 0.f, 0.f);
        }
      }
    }
    __syncthreads();
#pragma unroll
    for (int i = 0; i < 4; i++)
      gload_lds16(BT + (size_t)(n0 + i * 32 + r0) * ldb + kb + gsl * 8,
                  lB + i * 2048);
    if constexpr (AF32) {
#pragma unroll
      for (int i = 0; i < 4; i++)
        *(bf16x8*)(&As[0][0] + (size_t)(i * 256 + t) * 8) = cvt8(va[i][0], va[i][1]);
    } else {
#pragma unroll
      for (int i = 0; i < 4; i++)
        gload_lds16(A + (size_t)(m0 + i * 32 + r0) * lda + kb + gsl * 8,
                    lA + i * 2048);
    }
    __syncthreads();

#pragma unroll
    for (int ks = 0; ks < 2; ks++) {
      bf16x8 af[4], bfr[4];
#pragma unroll
      for (int i = 0; i < 4; i++) {
        int row = wm + i * 16 + l15;
        int off = (ks * 64 + q * 16) ^ ((l15 & 7) << 4);
        af[i] = *(const bf16x8*)((const char*)&As[row][0] + off);
      }
#pragma unroll
      for (int j = 0; j < 4; j++) {
        int row = wn + j * 16 + l15;
        int off = (ks * 64 + q * 16) ^ ((l15 & 7) << 4);
        bfr[j] = *(const bf16x8*)((const char*)&Bs[row][0] + off);
      }
#pragma unroll
      for (int i = 0; i < 4; i++)
#pragma unroll
        for (int j = 0; j < 4; j++)
          acc[i][j] = __builtin_amdgcn_mfma_f32_16x16x32_bf16(af[i], bfr[j],
                                                              acc[i][j], 0, 0, 0);
    }
  }

  if constexpr (EPI == 0) {
    // ---- LDS-staged coalesced epilogue (fp32) ----
    float* sc = (float*)&As[0][0];
    float* Cp = (float*)Cv + (size_t)b * sCb + (size_t)s * sCs;
#pragma unroll
    for (int ck = 0; ck < 4; ck++) {
      __syncthreads();
      if ((wid >> 1) == (ck >> 1)) {  // owner waves: rows [ck*32, ck*32+32)
        int ib = (ck & 1) * 2;
#pragma unroll
        for (int ii = 0; ii < 2; ii++) {
          int i = ib + ii;
          int rl = ii * 16 + q * 4;
#pragma unroll
          for (int j = 0; j < 4; j++) {
            int c = wn + j * 16 + l15;
#pragma unroll
            for (int r4 = 0; r4 < 4; r4++)
              sc[(rl + r4) * 128 + c] = acc[i][j][r4];
          }
        }
      }
      __syncthreads();
      int rbase0 = m0 + ck * 32;
#pragma unroll
      for (int i = 0; i < 4; i++) {
        int idx = i * 256 + t;      // float4 index in [0, 1024)
        int r = idx >> 5;           // 32 float4 per 128-col row
        int c4 = idx & 31;
        int gr = rbase0 + r;
        if (gr < M) {
          f32x4 v = *(const f32x4*)(sc + idx * 4);
          f32x4* dst = (f32x4*)(Cp + (size_t)gr * ldc) + (n0 >> 2) + c4;
          if (NTS) __builtin_nontemporal_store(v, dst);
          else *dst = v;
        }
      }
    }
  } else {
#pragma unroll
    for (int i = 0; i < 4; i++) {
      int rbase = m0 + wm + i * 16 + q * 4;
#pragma unroll
      for (int j = 0; j < 4; j++) {
        int c = n0 + wn + j * 16 + l15;
#pragma unroll
        for (int r4 = 0; r4 < 4; r4++) {
          int r = rbase + r4;
          if (r < M) {
            float val = acc[i][j][r4];
            if (EPI == 2) {
              float w = W[(size_t)r * N + c];
              bf16_t* Cp = (bf16_t*)Cv + (size_t)b * sCb;
              Cp[(size_t)r * ldc + c] = (bf16_t)(val * w);
            } else {
              bf16_t* Cp = (bf16_t*)Cv + (size_t)b * sCb;
              Cp[(size_t)r * ldc + c] = (bf16_t)val;
            }
          }
        }
      }
    }
  }
}

// ---------------- row softmax, L = 4096 (16 elems/thread, 256 threads) -----
// MODE 0: fp32 out (may alias in)
// MODE 1: bf16 out
// MODE 2: fp32 out (may alias in) + bf16 copy to out2 — all >L3 streams,
//         nt loads/stores (round-9 policy; round-10 cacheable variant −49 us)
// in row  = blockIdx.y * gridDim.x + blockIdx.x
// out row = blockIdx.y * ostr      + blockIdx.x   (ostr: padded batch stride)
template <int MODE>
__global__ __launch_bounds__(256) void softmax_rows(
    const float* __restrict__ in, void* __restrict__ out,
    bf16_t* __restrict__ out2, int L, int ostr) {
  long row_in = (long)blockIdx.y * gridDim.x + blockIdx.x;
  long row_out = (long)blockIdx.y * ostr + blockIdx.x;
  const float* ip = in + row_in * L;
  int t = threadIdx.x;
  int lane = t & 63, wid = t >> 6;
  f32x4 v[4];
  float m = -3.4e38f;
#pragma unroll
  for (int c = 0; c < 4; c++) {
    if (MODE == 2)
      v[c] = __builtin_nontemporal_load((const f32x4*)ip + c * 256 + t);
    else
      v[c] = ((const f32x4*)ip)[c * 256 + t];
    m = fmaxf(m, fmaxf(fmaxf(v[c][0], v[c][1]), fmaxf(v[c][2], v[c][3])));
  }
#pragma unroll
  for (int off = 1; off < 64; off <<= 1) m = fmaxf(m, __shfl_xor(m, off));
  __shared__ float redm[4];
  __shared__ float reds[4];
  if (lane == 0) redm[wid] = m;
  __syncthreads();
  m = fmaxf(fmaxf(redm[0], redm[1]), fmaxf(redm[2], redm[3]));
  float s = 0.0f;
#pragma unroll
  for (int c = 0; c < 4; c++) {
    v[c][0] = __expf(v[c][0] - m);
    v[c][1] = __expf(v[c][1] - m);
    v[c][2] = __expf(v[c][2] - m);
    v[c][3] = __expf(v[c][3] - m);
    s += (v[c][0] + v[c][1]) + (v[c][2] + v[c][3]);
  }
#pragma unroll
  for (int off = 1; off < 64; off <<= 1) s += __shfl_xor(s, off);
  if (lane == 0) reds[wid] = s;
  __syncthreads();
  s = (reds[0] + reds[1]) + (reds[2] + reds[3]);
  float inv = 1.0f / s;
  if (MODE == 1) {
    bf16_t* op = (bf16_t*)out + row_out * L;
#pragma unroll
    for (int c = 0; c < 4; c++) {
      bf16x4 o;
      o[0] = (bf16_t)(v[c][0] * inv);
      o[1] = (bf16_t)(v[c][1] * inv);
      o[2] = (bf16_t)(v[c][2] * inv);
      o[3] = (bf16_t)(v[c][3] * inv);
      *(bf16x4*)(op + ((size_t)c * 256 + t) * 4) = o;
    }
  } else {
    float* op = (float*)out + row_out * L;
#pragma unroll
    for (int c = 0; c < 4; c++) {
      f32x4 o = v[c] * inv;
      if (MODE == 2) {
        __builtin_nontemporal_store(o, (f32x4*)op + c * 256 + t);
        bf16x4 ob;
        ob[0] = (bf16_t)o[0]; ob[1] = (bf16_t)o[1];
        ob[2] = (bf16_t)o[2]; ob[3] = (bf16_t)o[3];
        __builtin_nontemporal_store(ob, (bf16x4*)(out2 + row_out * L) + c * 256 + t);
      } else {
        ((f32x4*)op)[c * 256 + t] = o;
      }
    }
  }
}

extern "C" void kernel_launch(void* const* d_in, const int* in_sizes, int n_in,
                              void* d_out, int out_size, void* d_ws, size_t ws_size,
                              hipStream_t stream) {
  const int B = 4, D = 512, L = 4096, N1 = 1167, N2 = 8921;
  const int N1P = 1280;  // padded N1: multiple of 128, row stride
  const int N1K = 1216;  // K extent for step 6 (smallest multiple of 64 >= N1)
  const int M2P = 8960;  // M-padded N2 (multiple of 256)
  const long SLAB5 = (long)D * N1P;  // step-5' split-partial slab (f32 elems)
  const float* H = (const float*)d_in[0];
  const float* Q1w = (const float*)d_in[1];
  const float* Q2w = (const float*)d_in[2];
  const float* Q12w = (const float*)d_in[3];
  float* C2 = (float*)d_out;                  // [B, N2, D] fp32
  float* A2 = C2 + (size_t)B * N2 * D;        // [B, N2, L] fp32 (E2 in place)

  char* ws = (char*)d_ws;
  size_t off = 0;
  auto alloc = [&](size_t bytes) -> void* {
    void* p = ws + off;
    off = (off + bytes + 255) & ~(size_t)255;
    return p;
  };
  bf16_t* Hb   = (bf16_t*)alloc((size_t)B * D * L * 2);
  bf16_t* HTb  = (bf16_t*)alloc((size_t)B * L * D * 2);
  bf16_t* Q1b  = (bf16_t*)alloc((size_t)N1P * D * 2);               // M-padded
  bf16_t* Q12b = (bf16_t*)alloc((size_t)M2P * N1P * 2);             // M+K padded
  float*  E1   = (float*)alloc((size_t)B * N1 * L * 4);
  bf16_t* A1b  = (bf16_t*)alloc((size_t)B * N1P * L * 2);           // [B][1280][L]
  bf16_t* C1Tb = (bf16_t*)alloc((size_t)B * D * N1P * 2);           // [B][512][1280]
  bf16_t* Q2b  = (bf16_t*)alloc(((size_t)B * N2 + 64) * D * 2);     // tail slop
  float*  P5   = (float*)alloc((size_t)B * 4 * SLAB5 * 4);          // 5' partials
  // bf16 copy of A2 for the step-9 GEMM (tail slop covers M-pad overreads of
  // the unguarded global_load_lds in the last batch). Guarded by ws_size.
  size_t a2b_bytes = ((size_t)B * N2 + 128) * (size_t)L * 2;
  bool useA2b = (ws_size > 0) && (off + a2b_bytes <= ws_size);
  bf16_t* A2b = (bf16_t*)alloc(a2b_bytes);

  // 1. bf16 cast of H + transpose
  cast_transpose_H<<<dim3(L / 32, D / 32, B), dim3(32, 8), 0, stream>>>(H, Hb, HTb, D, L);
  // 2. weight casts (grid.y = exact source rows; pad rows zero-filled after)
  cast_w_pad<<<dim3((D + 255) / 256, N1), 256, 0, stream>>>(Q1w, Q1b, D, D);
  zero_rows<<<dim3(((N1P - N1) * D / 8 + 255) / 256, 1), 256, 0, stream>>>(
      Q1b, N1, N1P - N1, 0, D);
  cast_w_pad<<<dim3((N1P + 255) / 256, N2), 256, 0, stream>>>(Q12w, Q12b, N1, N1P);
  zero_rows<<<dim3(((N1P - N1) * L / 8 + 255) / 256, B), 256, 0, stream>>>(
      A1b, N1, N1P - N1, (long)N1P, L);
  // 3. E1[b] = Q1 @ H[b]   (M=N1, N=L, K=D; BT = HT) [128^2, nt — r9 policy]
  gemm_bt<bf16_t, 0, true, 1><<<dim3(N1P / BM, L / BN, B), 256, 0, stream>>>(
      Q1b, 0, HTb, (long)L * D, E1, (long)N1 * L, nullptr, N1, L, D, D, D, L, 0);
  // 4. A1 = softmax(E1) -> bf16 rows [b*N1P + r]
  softmax_rows<1><<<dim3(N1, B), 256, 0, stream>>>(E1, A1b, nullptr, L, N1P);
  // 5'. C1T[b][d][n] = sum_l H[b,d,l] * A1[b,n,l]  (M=D, N=N1P, K=L)
  //     split-K=4 over L (640 blocks); cacheable partials, reduce -> bf16.
  gemm_bt<bf16_t, 0, false, 4><<<dim3(D / BM, N1P / BN, B * 4), 256, 0, stream>>>(
      Hb, (long)D * L, A1b, (long)N1P * L, P5, 4 * SLAB5, nullptr,
      D, N1P, L / 4, L, L, N1P, SLAB5);
  reduce4_bf16<<<dim3((SLAB5 / 4 + 255) / 256, B), 256, 0, stream>>>(P5, C1Tb, SLAB5);
  // 6. Q2[b] = (Q12 @ C1) * Q2w -> bf16  (M=N2, N=D, K=N1K; strides N1P) [128^2]
  gemm_bt<bf16_t, 2, true, 1><<<dim3(M2P / BM, D / BN, B), 256, 0, stream>>>(
      Q12b, 0, C1Tb, (long)D * N1P, Q2b, (long)N2 * D, Q2w, N2, D, N1K, N1P, N1P, D, 0);
  // 7. E2[b] = Q2 @ H[b] -> fp32 into A2 region  (M=N2, N=L, K=D)
  //    [256^2 8-phase, 2240 blocks, nt — r9 policy]
  gemm256_bt<0, true><<<dim3(M2P / 256, L / 256, B), 512, 0, stream>>>(
      Q2b, (long)N2 * D, HTb, (long)L * D, A2, (long)N2 * L, nullptr, N2, L, D, D, D, L);
  if (useA2b) {
    // 8. A2 = softmax(E2) in place (fp32) + bf16 copy  (nt streams — r9)
    softmax_rows<2><<<dim3(B * N2, 1), 256, 0, stream>>>(A2, A2, A2b, L, 0);
    // 9. C2[b] = A2 @ H[b]^T  (M=N2, N=D, K=L; bf16 A) [256^2 8ph ISOLATED:
    //    NT=64 deep K-loop, 280 blocks ~1.09 rounds; r8 bundle couldn't
    //    attribute — this round tests it alone]
    gemm256_bt<0, true><<<dim3(M2P / 256, D / 256, B), 512, 0, stream>>>(
        A2b, (long)N2 * L, Hb, (long)D * L, C2, (long)N2 * D, nullptr, N2, D, L, L, L, D);
  } else {
    // fallback: workspace too small for A2b
    softmax_rows<0><<<dim3(B * N2, 1), 256, 0, stream>>>(A2, A2, nullptr, L, 0);
    gemm_bt<float, 0, true, 1><<<dim3(M2P / BM, D / BN, B), 256, 0, stream>>>(
        A2, (long)N2 * L, Hb, (long)D * L, C2, (long)N2 * D, nullptr, N2, D, L, L, L, D, 0);
  }
}